// Round 15
// baseline (994.645 us; speedup 1.0000x reference)
//
#include <hip/hip_runtime.h>
#include <math.h>

#define DD 64
typedef unsigned short ushort_t;
typedef __attribute__((ext_vector_type(8))) short bf16x8;
typedef __attribute__((ext_vector_type(4))) float f32x4;

#define GEPW 16
#define TPW 8
#define EGRID 4096
#define TGRID 2048

__device__ __forceinline__ float silu_f(float x) {
    return x / (1.0f + __expf(-x));
}

__device__ __forceinline__ unsigned f32_to_bf16_rne(float x) {
    unsigned u = __float_as_uint(x);
    unsigned r = ((u >> 16) & 1u) + 0x7fffu;
    return (u + r) >> 16;
}

__device__ __forceinline__ float bf16_to_f32(ushort_t v) {
    return __uint_as_float(((unsigned)v) << 16);
}

__device__ __forceinline__ float2 bf2_lo_hi(unsigned u) {
    return make_float2(__uint_as_float(u << 16), __uint_as_float(u & 0xffff0000u));
}

__device__ __forceinline__ void gload_lds4(const void* gsrc, void* lds_base) {
    __builtin_amdgcn_global_load_lds(
        (const __attribute__((address_space(1))) void*)gsrc,
        (__attribute__((address_space(3))) void*)lds_base,
        4, 0, 0);
}

#define RFL(x) __builtin_amdgcn_readfirstlane(x)

// ---------------- sort chain (standalone parts) ----------------
__global__ __launch_bounds__(256) void hist_kernel(const int* __restrict__ eidx,
                                                   int* __restrict__ counts, int E) {
    int i = blockIdx.x * 256 + threadIdx.x;
    if (i < E) atomicAdd(&counts[((const int2*)eidx)[i].x], 1);
}

__global__ __launch_bounds__(1024) void scan_kernel(const int* __restrict__ counts,
                                                    int* __restrict__ cursor, int N) {
    __shared__ int part[1024];
    int tid = threadIdx.x;
    int CH = (N + 1023) / 1024;
    int lo = tid * CH, hi = lo + CH; if (hi > N) hi = N; if (lo > N) lo = N;
    int s = 0;
    for (int i = lo; i < hi; ++i) s += counts[i];
    part[tid] = s;
    __syncthreads();
    for (int d = 1; d < 1024; d <<= 1) {
        int v = (tid >= d) ? part[tid - d] : 0;
        __syncthreads();
        part[tid] += v;
        __syncthreads();
    }
    int run = (tid == 0) ? 0 : part[tid - 1];
    for (int i = lo; i < hi; ++i) {
        cursor[i] = run;
        run += counts[i];
    }
}

// ---------------- fused prep: scatter2 | node_transform | node_vector
__global__ __launch_bounds__(256) void fused_prep_kernel(
    const int* __restrict__ eidx, const float* __restrict__ pos,
    int* __restrict__ cursor, int2* __restrict__ eperm, float* __restrict__ relg,
    const float* __restrict__ ns, const float* __restrict__ nc,
    const float* __restrict__ Ws1, const float* __restrict__ Wc1,
    ushort_t* __restrict__ Abf, ushort_t* __restrict__ Bbf,
    float* __restrict__ C, float* __restrict__ Dm, float* __restrict__ out1,
    const float* __restrict__ nv, const float* __restrict__ WV, const float* __restrict__ bV,
    float* __restrict__ out0, float* __restrict__ out2,
    unsigned* __restrict__ nv01p, ushort_t* __restrict__ nv2bf,
    int N, int E, int sblocks)
{
    __shared__ __align__(16) char smem[69632];
    int tid = threadIdx.x;
    int bx = blockIdx.x;

    if (bx < sblocks) {
        // -------- scatter2 --------
        int i = bx * 256 + tid;
        if (i < E) {
            int2 p = ((const int2*)eidx)[i];
            int dst = atomicAdd(&cursor[p.x], 1);
            eperm[dst] = p;
            relg[3 * (size_t)dst + 0] = pos[(size_t)p.y * 3 + 0] - pos[(size_t)p.x * 3 + 0];
            relg[3 * (size_t)dst + 1] = pos[(size_t)p.y * 3 + 1] - pos[(size_t)p.x * 3 + 1];
            relg[3 * (size_t)dst + 2] = pos[(size_t)p.y * 3 + 2] - pos[(size_t)p.x * 3 + 2];
        }
        return;
    }
    if (bx < sblocks + 2048) {
        // -------- node_transform --------
        int blk = bx - sblocks;
        float* w1   = (float*)smem;                  // 32 KiB
        float* wc1s = (float*)(smem + 32768);        // 32 KiB
        float* xs   = (float*)(smem + 65536);        // 2 KiB  [(wave*2+s)*64+lane]
        float* ys   = (float*)(smem + 67584);        // 2 KiB
        for (int i = tid; i < 128 * 64 / 4; i += 256) {
            ((float4*)w1)[i]   = ((const float4*)Ws1)[i];
            ((float4*)wc1s)[i] = ((const float4*)Wc1)[i];
        }
        __syncthreads();
        int wave = tid >> 6, lane = tid & 63;
        for (int nb = blk * 8; nb < N; nb += 2048 * 8) {
            int n0 = nb + wave * 2;
            #pragma unroll
            for (int s = 0; s < 2; ++s) {
                int n = n0 + s;
                float xv = 0.f, yv = 0.f;
                if (n < N) { xv = ns[(size_t)n * DD + lane]; yv = nc[(size_t)n * DD + lane]; }
                xs[(wave * 2 + s) * 64 + lane] = xv;
                ys[(wave * 2 + s) * 64 + lane] = yv;
            }
            float aA[2] = {0.f, 0.f}, aB[2] = {0.f, 0.f}, aC[2] = {0.f, 0.f}, aD[2] = {0.f, 0.f};
            for (int k = 0; k < 64; ++k) {
                float wa  = w1[k * 64 + lane];
                float wb  = w1[(64 + k) * 64 + lane];
                float wca = wc1s[k * 64 + lane];
                float wcb = wc1s[(64 + k) * 64 + lane];
                #pragma unroll
                for (int s = 0; s < 2; ++s) {
                    float xk = xs[(wave * 2 + s) * 64 + k];
                    float yk = ys[(wave * 2 + s) * 64 + k];
                    aA[s] += xk * wa;  aB[s] += xk * wb;
                    aC[s] += yk * wca; aD[s] += yk * wcb;
                }
            }
            #pragma unroll
            for (int s = 0; s < 2; ++s) {
                int n = n0 + s;
                if (n < N) {
                    Abf[(size_t)n * DD + lane] = (ushort_t)f32_to_bf16_rne(aA[s]);
                    Bbf[(size_t)n * DD + lane] = (ushort_t)f32_to_bf16_rne(aB[s]);
                    C[(size_t)n * DD + lane]  = aC[s];
                    Dm[(size_t)n * DD + lane] = aD[s];
                    out1[(size_t)n * DD + lane] = ys[(wave * 2 + s) * 64 + lane];
                }
            }
            __syncthreads();
        }
        return;
    }
    // -------- node_vector --------
    {
        int blk = bx - sblocks - 2048;
        float* wv = (float*)smem;                    // 16 KiB
        float* vs = (float*)(smem + 16384);          // 6 KiB [((wave*2+s)*3+r)*64+lane]
        for (int i = tid; i < 64 * 64 / 4; i += 256)
            ((float4*)wv)[i] = ((const float4*)WV)[i];
        __syncthreads();
        int wave = tid >> 6, lane = tid & 63;
        float bVj = bV[lane];
        for (int nb = blk * 8; nb < N; nb += 2048 * 8) {
            int n0 = nb + wave * 2;
            #pragma unroll
            for (int s = 0; s < 2; ++s) {
                int n = n0 + s;
                float v0 = 0.f, v1 = 0.f, v2 = 0.f;
                if (n < N) {
                    v0 = nv[((size_t)n * 3 + 0) * DD + lane];
                    v1 = nv[((size_t)n * 3 + 1) * DD + lane];
                    v2 = nv[((size_t)n * 3 + 2) * DD + lane];
                }
                vs[((wave * 2 + s) * 3 + 0) * 64 + lane] = v0;
                vs[((wave * 2 + s) * 3 + 1) * 64 + lane] = v1;
                vs[((wave * 2 + s) * 3 + 2) * 64 + lane] = v2;
            }
            float a0[2], a1[2], a2[2];
            #pragma unroll
            for (int s = 0; s < 2; ++s) { a0[s] = bVj; a1[s] = bVj; a2[s] = bVj; }
            for (int k = 0; k < 64; ++k) {
                float w = wv[k * 64 + lane];
                #pragma unroll
                for (int s = 0; s < 2; ++s) {
                    a0[s] += vs[((wave * 2 + s) * 3 + 0) * 64 + k] * w;
                    a1[s] += vs[((wave * 2 + s) * 3 + 1) * 64 + k] * w;
                    a2[s] += vs[((wave * 2 + s) * 3 + 2) * 64 + k] * w;
                }
            }
            #pragma unroll
            for (int s = 0; s < 2; ++s) {
                int n = n0 + s;
                if (n < N) {
                    float norm = sqrtf(a0[s] * a0[s] + a1[s] * a1[s] + a2[s] * a2[s]);
                    float x = ns[(size_t)n * DD + lane];
                    out0[(size_t)n * DD + lane] = x * (1.f + norm);
                    float v0 = vs[((wave * 2 + s) * 3 + 0) * 64 + lane];
                    float v1 = vs[((wave * 2 + s) * 3 + 1) * 64 + lane];
                    float v2 = vs[((wave * 2 + s) * 3 + 2) * 64 + lane];
                    out2[((size_t)n * 3 + 0) * DD + lane] = v0;
                    out2[((size_t)n * 3 + 1) * DD + lane] = v1;
                    out2[((size_t)n * 3 + 2) * DD + lane] = v2;
                    nv01p[(size_t)n * DD + lane] = f32_to_bf16_rne(v0) | (f32_to_bf16_rne(v1) << 16);
                    nv2bf[(size_t)n * DD + lane] = (ushort_t)f32_to_bf16_rne(v2);
                }
            }
            __syncthreads();
        }
    }
}

// ---------------- fused edge | triplet
__global__ __launch_bounds__(256) void fused_et_kernel(
    const ushort_t* __restrict__ Abf, const ushort_t* __restrict__ Bbf,
    const unsigned* __restrict__ nv01p, const ushort_t* __restrict__ nv2bf,
    const float* __restrict__ relg, const int2* __restrict__ eperm,
    const float* __restrict__ bs1, const float* __restrict__ Ws2, const float* __restrict__ bs2,
    const float* __restrict__ C, const float* __restrict__ Dm,
    const float* __restrict__ pos, const int* __restrict__ tidx,
    const float* __restrict__ bc1, const float* __restrict__ Wc2, const float* __restrict__ bc2,
    float* __restrict__ out0, float* __restrict__ out1, float* __restrict__ out2,
    int E, int T)
{
    __shared__ __align__(16) char smem[50432];
    int tid = threadIdx.x;

    if (blockIdx.x < EGRID) {
        // ================= edge path (round-14 body) =================
        unsigned* w2frag = (unsigned*)smem;                    // 24576 B
        ushort_t* stAB   = (ushort_t*)(smem + 24576);          // 16384 B [(wave*16+e)*128+x]
        ushort_t* stNV2  = (ushort_t*)(smem + 40960);          // 8448 B  [(wave*8+p)*132+x]
        float*    relL   = (float*)(smem + 49408);             // 1024 B  [wave*64+x]
        for (int i = tid; i < 12 * 2 * 64; i += 256) {
            int t  = i >> 7;
            int kk = (i >> 6) & 1;
            int l  = i & 63;
            int k0 = kk * 32 + (l >> 4) * 8;
            int col = t * 16 + (l & 15);
            #pragma unroll
            for (int jp = 0; jp < 4; ++jp) {
                float a = Ws2[(size_t)(k0 + 2 * jp) * 192 + col];
                float b = Ws2[(size_t)(k0 + 2 * jp + 1) * 192 + col];
                w2frag[i * 4 + jp] = f32_to_bf16_rne(a) | (f32_to_bf16_rne(b) << 16);
            }
        }
        __syncthreads();
        int wave = RFL(tid >> 6);
        int lane = tid & 63;
        float b1 = bs1[lane];
        float b2v_t[4], b2e_t[4], b2s_t[4];
        #pragma unroll
        for (int t = 0; t < 4; ++t) {
            b2v_t[t] = bs2[t * 16 + (lane & 15)];
            b2e_t[t] = bs2[64 + t * 16 + (lane & 15)];
            b2s_t[t] = bs2[128 + t * 16 + (lane & 15)];
        }
        int bid = blockIdx.x;
        int cpx = EGRID >> 3;
        int swz = (bid & 7) * cpx + (bid >> 3);

        long nG = ((long)E + GEPW - 1) / GEPW;
        for (long g = (long)swz * 4 + wave; g < nG; g += (long)EGRID * 4) {
            long e0b = g * GEPW;
            int i0a[GEPW], i1a[GEPW];
            #pragma unroll
            for (int e = 0; e < GEPW; ++e) {
                long eid = e0b + e; if (eid >= E) eid = E - 1;
                int2 p = eperm[eid];
                i0a[e] = RFL(p.x); i1a[e] = RFL(p.y);
            }
            int vi_all = 0, vi1_all = 0;
            #pragma unroll
            for (int e = 0; e < GEPW; ++e) {
                vi_all  = (lane == e) ? i0a[e] : vi_all;
                vi1_all = (lane == e) ? i1a[e] : vi1_all;
            }
            // phase 1: AB gloads (oldest 16)
            #pragma unroll
            for (int e = 0; e < GEPW; ++e) {
                const char* srcAB = (lane < 32)
                    ? ((const char*)Abf + (size_t)i0a[e] * 128 + lane * 4)
                    : ((const char*)Bbf + (size_t)i1a[e] * 128 + (lane - 32) * 4);
                gload_lds4(srcAB, stAB + (wave * GEPW + e) * 128);
            }
            __builtin_amdgcn_sched_barrier(0);
            // phase 2: nv2 (8) + rel (1) + nv01 VGPR loads (16)
            #pragma unroll
            for (int p2 = 0; p2 < GEPW / 2; ++p2) {
                const char* src2 = (lane < 32)
                    ? ((const char*)nv2bf + (size_t)i1a[2 * p2] * 128 + lane * 4)
                    : ((const char*)nv2bf + (size_t)i1a[2 * p2 + 1] * 128 + (lane - 32) * 4);
                gload_lds4(src2, stNV2 + (wave * (GEPW / 2) + p2) * 132);
            }
            gload_lds4((const char*)relg + e0b * 12 + lane * 4, relL + wave * 64);
            int eL0 = (lane >> 4) * 4;
            unsigned nv01r[4][4];
            #pragma unroll
            for (int rg = 0; rg < 4; ++rg) {
                int i1s = __builtin_amdgcn_ds_bpermute((eL0 + rg) * 4, vi1_all);
                const char* basep = (const char*)nv01p + (size_t)(unsigned)i1s * 256 + (lane & 15) * 4;
                nv01r[rg][0] = *(const unsigned*)(basep);
                nv01r[rg][1] = *(const unsigned*)(basep + 64);
                nv01r[rg][2] = *(const unsigned*)(basep + 128);
                nv01r[rg][3] = *(const unsigned*)(basep + 192);
            }
            __builtin_amdgcn_sched_barrier(0);
            asm volatile("s_waitcnt vmcnt(25)" ::: "memory");
            __builtin_amdgcn_sched_barrier(0);
            // h phase
            #pragma unroll
            for (int e = 0; e < GEPW; ++e) {
                float a = bf16_to_f32(stAB[(wave * GEPW + e) * 128 + lane]);
                float b = bf16_to_f32(stAB[(wave * GEPW + e) * 128 + 64 + lane]);
                float h = silu_f(a + b + b1);
                *(float*)((char*)(stAB + (wave * GEPW + e) * 128) + ((lane * 4) ^ ((e & 7) << 5))) = h;
            }
            __builtin_amdgcn_sched_barrier(0);
            // MFMA
            f32x4 acc[12];
            f32x4 zz = {0.f, 0.f, 0.f, 0.f};
            #pragma unroll
            for (int t = 0; t < 12; ++t) acc[t] = zz;
            int row = lane & 15;
            #pragma unroll
            for (int kk = 0; kk < 2; ++kk) {
                int coff = (kk * 128 + ((lane >> 4) * 32)) ^ ((row & 7) << 5);
                const char* hp = (const char*)(stAB + (wave * GEPW + row) * 128) + coff;
                float4 lo = *(const float4*)hp;
                float4 hi = *(const float4*)(hp + 16);
                unsigned a0, a1, a2, a3;
                asm("v_cvt_pk_bf16_f32 %0, %1, %2" : "=v"(a0) : "v"(lo.x), "v"(lo.y));
                asm("v_cvt_pk_bf16_f32 %0, %1, %2" : "=v"(a1) : "v"(lo.z), "v"(lo.w));
                asm("v_cvt_pk_bf16_f32 %0, %1, %2" : "=v"(a2) : "v"(hi.x), "v"(hi.y));
                asm("v_cvt_pk_bf16_f32 %0, %1, %2" : "=v"(a3) : "v"(hi.z), "v"(hi.w));
                union { unsigned u[4]; bf16x8 v; } af;
                af.u[0] = a0; af.u[1] = a1; af.u[2] = a2; af.u[3] = a3;
                #pragma unroll
                for (int t = 0; t < 12; ++t) {
                    bf16x8 bf = *(const bf16x8*)&w2frag[((t * 2 + kk) * 64 + lane) * 4];
                    acc[t] = __builtin_amdgcn_mfma_f32_16x16x32_bf16(af.v, bf, acc[t], 0, 0, 0);
                }
            }
            asm volatile("s_waitcnt vmcnt(0)" ::: "memory");
            __builtin_amdgcn_sched_barrier(0);
            // scatter with in-register merge
            float aS[4]  = {0.f, 0.f, 0.f, 0.f};
            float aV0[4] = {0.f, 0.f, 0.f, 0.f};
            float aV1[4] = {0.f, 0.f, 0.f, 0.f};
            float aV2[4] = {0.f, 0.f, 0.f, 0.f};
            int icur = __builtin_amdgcn_ds_bpermute(eL0 * 4, vi_all);
            #pragma unroll
            for (int rg = 0; rg < 4; ++rg) {
                int e = eL0 + rg;
                int i0 = __builtin_amdgcn_ds_bpermute(e * 4, vi_all);
                bool ok = (e0b + e) < E;
                if (i0 != icur) {
                    #pragma unroll
                    for (int t = 0; t < 4; ++t) {
                        int dim = t * 16 + (lane & 15);
                        unsafeAtomicAdd(&out0[(size_t)(unsigned)icur * 64u + dim], aS[t]);
                        unsafeAtomicAdd(&out2[((size_t)(unsigned)icur * 3u + 0) * 64u + dim], aV0[t]);
                        unsafeAtomicAdd(&out2[((size_t)(unsigned)icur * 3u + 1) * 64u + dim], aV1[t]);
                        unsafeAtomicAdd(&out2[((size_t)(unsigned)icur * 3u + 2) * 64u + dim], aV2[t]);
                        aS[t] = 0.f; aV0[t] = 0.f; aV1[t] = 0.f; aV2[t] = 0.f;
                    }
                    icur = i0;
                }
                if (ok) {
                    float r0v = relL[wave * 64 + e * 3 + 0];
                    float r1v = relL[wave * 64 + e * 3 + 1];
                    float r2v = relL[wave * 64 + e * 3 + 2];
                    #pragma unroll
                    for (int t = 0; t < 4; ++t) {
                        int dim = t * 16 + (lane & 15);
                        float gv = acc[t][rg]     + b2v_t[t];
                        float ge = acc[4 + t][rg] + b2e_t[t];
                        float ss = acc[8 + t][rg] + b2s_t[t];
                        float2 vv = bf2_lo_hi(nv01r[rg][t]);
                        float v2 = bf16_to_f32(stNV2[(wave * (GEPW / 2) + (e >> 1)) * 132 + (e & 1) * 64 + dim]);
                        aS[t]  += ss;
                        aV0[t] += gv * vv.x + ge * r0v;
                        aV1[t] += gv * vv.y + ge * r1v;
                        aV2[t] += gv * v2   + ge * r2v;
                    }
                }
            }
            #pragma unroll
            for (int t = 0; t < 4; ++t) {
                int dim = t * 16 + (lane & 15);
                unsafeAtomicAdd(&out0[(size_t)(unsigned)icur * 64u + dim], aS[t]);
                unsafeAtomicAdd(&out2[((size_t)(unsigned)icur * 3u + 0) * 64u + dim], aV0[t]);
                unsafeAtomicAdd(&out2[((size_t)(unsigned)icur * 3u + 1) * 64u + dim], aV1[t]);
                unsafeAtomicAdd(&out2[((size_t)(unsigned)icur * 3u + 2) * 64u + dim], aV2[t]);
            }
        }
        return;
    }

    // ================= triplet path (round-14 body) =================
    {
        float* wT  = (float*)smem;                   // 16384 B
        float* stC = (float*)(smem + 16384);         // 8192 B  [(wave*TPW+e)*64+lane]
        float* stD = (float*)(smem + 24576);         // 24576 B [((wave*TPW+e)*3+r)*64+lane]
        for (int i = tid; i < 64 * 64 / 4; i += 256)
            ((float4*)wT)[i] = ((const float4*)Wc2)[i];
        __syncthreads();
        int wave = RFL(tid >> 6);
        int lane = tid & 63;
        float b1 = bc1[lane];
        float b2 = bc2[lane] * 3.0f;
        long tb = blockIdx.x - EGRID;
        for (long bb = tb * (4 * TPW); bb < T; bb += (long)TGRID * (4 * TPW)) {
            long t0 = bb + wave * TPW;
            int ib[TPW], it1[TPW], it2[TPW], it3[TPW];
            #pragma unroll
            for (int e = 0; e < TPW; ++e) {
                long t = t0 + e;
                int b = 0, t1 = 0, t2 = 0, t3 = 0;
                if (t < T) { int4 q = ((const int4*)tidx)[t]; b = q.x; t1 = q.y; t2 = q.z; t3 = q.w; }
                ib[e]  = RFL(b);
                it1[e] = RFL(t1);
                it2[e] = RFL(t2);
                it3[e] = RFL(t3);
            }
            #pragma unroll
            for (int e = 0; e < TPW; ++e) {
                gload_lds4(C  + (size_t)ib[e]  * DD + lane, stC + (wave * TPW + e) * 64);
                gload_lds4(Dm + (size_t)it1[e] * DD + lane, stD + ((wave * TPW + e) * 3 + 0) * 64);
                gload_lds4(Dm + (size_t)it2[e] * DD + lane, stD + ((wave * TPW + e) * 3 + 1) * 64);
                gload_lds4(Dm + (size_t)it3[e] * DD + lane, stD + ((wave * TPW + e) * 3 + 2) * 64);
            }
            asm volatile("s_waitcnt vmcnt(0)" ::: "memory");
            float inv[TPW];
            #pragma unroll
            for (int e = 0; e < TPW; ++e) {
                float hb = stC[(wave * TPW + e) * 64 + lane] + b1;
                float h = silu_f(hb + stD[((wave * TPW + e) * 3 + 0) * 64 + lane])
                        + silu_f(hb + stD[((wave * TPW + e) * 3 + 1) * 64 + lane])
                        + silu_f(hb + stD[((wave * TPW + e) * 3 + 2) * 64 + lane]);
                stC[(wave * TPW + e) * 64 + lane] = h;
                int b = ib[e], t1 = it1[e], t2 = it2[e], t3 = it3[e];
                double pbx = pos[(size_t)b * 3], pby = pos[(size_t)b * 3 + 1], pbz = pos[(size_t)b * 3 + 2];
                double r1x = pbx - pos[(size_t)t1 * 3], r1y = pby - pos[(size_t)t1 * 3 + 1], r1z = pbz - pos[(size_t)t1 * 3 + 2];
                double r2x = pbx - pos[(size_t)t2 * 3], r2y = pby - pos[(size_t)t2 * 3 + 1], r2z = pbz - pos[(size_t)t2 * 3 + 2];
                double r3x = pbx - pos[(size_t)t3 * 3], r3y = pby - pos[(size_t)t3 * 3 + 1], r3z = pbz - pos[(size_t)t3 * 3 + 2];
                double cx = r2y * r3z - r2z * r3y;
                double cy = r2z * r3x - r2x * r3z;
                double cz = r2x * r3y - r2y * r3x;
                double stp = r1x * cx + r1y * cy + r1z * cz;
                inv[e] = (float)(1.0 / (stp + 0.01));
            }
            float acc[TPW];
            #pragma unroll
            for (int e = 0; e < TPW; ++e) acc[e] = 0.f;
            for (int k4 = 0; k4 < 64; k4 += 4) {
                float4 hk[TPW];
                #pragma unroll
                for (int e = 0; e < TPW; ++e) hk[e] = *(const float4*)&stC[(wave * TPW + e) * 64 + k4];
                #pragma unroll
                for (int kk = 0; kk < 4; ++kk) {
                    float wk = wT[(k4 + kk) * 64 + lane];
                    #pragma unroll
                    for (int e = 0; e < TPW; ++e) acc[e] += (&hk[e].x)[kk] * wk;
                }
            }
            #pragma unroll
            for (int e = 0; e < TPW; ++e) {
                long t = t0 + e;
                if (t >= T) break;
                unsafeAtomicAdd(&out1[(size_t)ib[e] * DD + lane], (acc[e] + b2) * inv[e]);
            }
        }
    }
}

extern "C" void kernel_launch(void* const* d_in, const int* in_sizes, int n_in,
                              void* d_out, int out_size, void* d_ws, size_t ws_size,
                              hipStream_t stream)
{
    const float* ns  = (const float*)d_in[0];
    const float* nc  = (const float*)d_in[1];
    const float* nv  = (const float*)d_in[2];
    const float* pos = (const float*)d_in[3];
    const int* eidx  = (const int*)d_in[4];
    const int* tidx  = (const int*)d_in[5];
    const float* Ws1 = (const float*)d_in[6];
    const float* bs1 = (const float*)d_in[7];
    const float* Ws2 = (const float*)d_in[8];
    const float* bs2 = (const float*)d_in[9];
    const float* Wc1 = (const float*)d_in[10];
    const float* bc1 = (const float*)d_in[11];
    const float* Wc2 = (const float*)d_in[12];
    const float* bc2 = (const float*)d_in[13];
    const float* WV  = (const float*)d_in[14];
    const float* bV  = (const float*)d_in[15];

    int N = in_sizes[0] / 64;
    int E = in_sizes[4] / 2;
    int T = in_sizes[5] / 4;

    float* out0 = (float*)d_out;
    float* out1 = out0 + (size_t)N * 64;
    float* out2 = out1 + (size_t)N * 64;

    float* C    = (float*)d_ws;
    float* Dm   = C + (size_t)N * 64;
    float* relg = Dm + (size_t)N * 64;                 // E*3 + 64 floats
    int2* eperm = (int2*)(relg + (size_t)E * 3 + 64);  // E int2
    int* counts = (int*)(eperm + (size_t)E);
    int* cursor = counts + N;
    unsigned* nv01p = (unsigned*)(cursor + N);         // N*64 uint
    ushort_t* Abf   = (ushort_t*)(nv01p + (size_t)N * 64);
    ushort_t* Bbf   = Abf + (size_t)N * 64;
    ushort_t* nv2bf = Bbf + (size_t)N * 64;

    int sblocks = (E + 255) / 256;

    hipMemsetAsync(counts, 0, (size_t)N * sizeof(int), stream);
    hist_kernel<<<sblocks, 256, 0, stream>>>(eidx, counts, E);
    scan_kernel<<<1, 1024, 0, stream>>>(counts, cursor, N);
    fused_prep_kernel<<<sblocks + 4096, 256, 0, stream>>>(
        eidx, pos, cursor, eperm, relg,
        ns, nc, Ws1, Wc1, Abf, Bbf, C, Dm, out1,
        nv, WV, bV, out0, out2, nv01p, nv2bf,
        N, E, sblocks);
    fused_et_kernel<<<EGRID + TGRID, 256, 0, stream>>>(
        Abf, Bbf, nv01p, nv2bf, relg, eperm,
        bs1, Ws2, bs2,
        C, Dm, pos, tidx, bc1, Wc2, bc2,
        out0, out1, out2, E, T);
}